// Round 7
// baseline (678.987 us; speedup 1.0000x reference)
//
#include <hip/hip_runtime.h>
#include <hip/hip_fp16.h>

#define RL(x) __builtin_amdgcn_readfirstlane(x)

typedef float f2 __attribute__((ext_vector_type(2)));

// packed dual-fp32 FMA: d = a*b + d (VOP3P, 2x fp32 per lane per instr)
static __device__ __forceinline__ void pkfma(f2& d, f2 a, f2 b) {
  asm("v_pk_fma_f32 %0, %1, %2, %0" : "+v"(d) : "v"(a), "v"(b));
}

// ---------------- weight prep: conv2/conv3 weights -> [ic][ky][ocg][o][kx] (4-oc groups) ----
// wt2n[((ic*4+ky)*16+ocg)*16 + o*4+kx] = w2[(ocg*4+o)*512 + ic*16 + ky*4 + kx]   (32768)
// wt3n[((ic*3+ky)*16+ocg)*12 + o*3+kx] = w3[(ocg*4+o)*576 + ic*9  + ky*3 + kx]   (36864)
__global__ __launch_bounds__(256) void wprep_k(const float* __restrict__ w2,
                                               const float* __restrict__ w3,
                                               float* __restrict__ wt2,
                                               float* __restrict__ wt3) {
  int i = blockIdx.x * 256 + threadIdx.x;
  if (i < 32768) {
    int t = i & 15, o = t >> 2, kx = t & 3;
    int r = i >> 4, ocg = r & 15, r2 = r >> 4, ky = r2 & 3, ic = r2 >> 2;
    wt2[i] = w2[(ocg * 4 + o) * 512 + ic * 16 + ky * 4 + kx];
  }
  if (i < 36864) {
    int t = i % 12, o = t / 3, kx = t - o * 3;
    int r = i / 12, ocg = r & 15, r2 = r >> 4, ky = r2 % 3, ic = r2 / 3;
    wt3[i] = w3[(ocg * 4 + o) * 576 + ic * 9 + ky * 3 + kx];
  }
}

// ---------------- conv1: x[1024,4,84,84] -> c1h[b][32*400] fp16, k=8, s=4 ----------------
// Pixels on lanes; weights in LDS as [ic,ky][kx][oc] so oc-PAIRS are contiguous
// (ds_read_b64 -> true float2). Inner loop = v_pk_fma_f32 over oc-pairs.
__global__ __launch_bounds__(256, 3) void conv1_k(const float* __restrict__ x,
                                                  const float* __restrict__ w,    // [32,4,8,8]
                                                  const float* __restrict__ bias,
                                                  __half* __restrict__ out) {
  __shared__ float wl[8192];
  const int b    = blockIdx.x;
  const int tid  = threadIdx.x;
  const int lane = tid & 63;
  const int g    = RL(tid >> 6);

  // stage: wl[(ic*8+ky)*256 + kx*32 + oc] = w[oc*256 + ic*64 + ky*8 + kx]
#pragma unroll
  for (int i = 0; i < 32; ++i) {
    int idx = tid + i * 256;
    int oc = idx >> 8, rem = idx & 255;
    int ic = rem >> 6, ky = (rem >> 3) & 7, kx = rem & 7;
    wl[(ic * 8 + ky) * 256 + kx * 32 + oc] = w[idx];
  }
  __syncthreads();

  int pv[7], ib[7];
#pragma unroll
  for (int s = 0; s < 7; ++s) {
    int p = lane + 64 * s;
    pv[s] = (p < 400);
    if (p > 399) p = 399;
    int py = p / 20, px = p - py * 20;
    ib[s] = py * 336 + px * 4;
  }

  f2 acc2[7][4];
#pragma unroll
  for (int s = 0; s < 7; ++s)
#pragma unroll
    for (int j = 0; j < 4; ++j) acc2[s][j] = (f2){0.f, 0.f};

  const float* xb = x + b * 28224;
#pragma unroll 1
  for (int ic = 0; ic < 4; ++ic) {
#pragma unroll 1
    for (int ky = 0; ky < 8; ++ky) {
      const float* wp = &wl[(ic * 8 + ky) * 256 + g * 8];
      f2 wk2[4][8];
#pragma unroll
      for (int kx = 0; kx < 8; ++kx)
#pragma unroll
        for (int j = 0; j < 4; ++j)
          wk2[j][kx] = *(const f2*)(wp + kx * 32 + 2 * j);
      const float* rp = xb + ic * 7056 + ky * 84;
#pragma unroll
      for (int s = 0; s < 7; ++s) {
        float4 a = *(const float4*)(rp + ib[s]);
        float4 c = *(const float4*)(rp + ib[s] + 4);
        float in8[8] = {a.x, a.y, a.z, a.w, c.x, c.y, c.z, c.w};
        f2 in2[8];
#pragma unroll
        for (int kx = 0; kx < 8; ++kx) in2[kx] = (f2){in8[kx], in8[kx]};
#pragma unroll
        for (int j = 0; j < 4; ++j)
#pragma unroll
          for (int kx = 0; kx < 8; ++kx)
            pkfma(acc2[s][j], in2[kx], wk2[j][kx]);
      }
    }
  }

  const float inv256 = 1.0f / 256.0f;
#pragma unroll
  for (int j = 0; j < 4; ++j) {
    float b0 = bias[g * 8 + 2 * j];
    float b1 = bias[g * 8 + 2 * j + 1];
    __half* op0 = out + (b * 32 + g * 8 + 2 * j) * 400;
    __half* op1 = op0 + 400;
#pragma unroll
    for (int s = 0; s < 7; ++s) {
      if (pv[s]) {
        float v0 = acc2[s][j].x * inv256 + b0;
        float v1 = acc2[s][j].y * inv256 + b1;
        op0[lane + 64 * s] = __float2half(v0 > 0.f ? v0 : 0.f);
        op1[lane + 64 * s] = __float2half(v1 > 0.f ? v1 : 0.f);
      }
    }
  }
}

// ---------------- t1: transpose c1h[1024][12800] -> c1t[12800][1024] (fp16) ----------------
__global__ __launch_bounds__(256) void t1_k(const __half* __restrict__ in,
                                            __half* __restrict__ out) {
  __shared__ __half t[64][65];
  const int kb = blockIdx.x * 64;
  const int bb = blockIdx.y * 64;
  const int lane = threadIdx.x & 63;
  const int ty   = threadIdx.x >> 6;
#pragma unroll
  for (int r = ty; r < 64; r += 4)
    t[r][lane] = in[(bb + r) * 12800 + kb + lane];
  __syncthreads();
#pragma unroll
  for (int r = ty; r < 64; r += 4)
    out[(kb + r) * 1024 + bb + lane] = t[lane][r];
}

// ---------------- conv2: c1t[12800][1024] -> c2t[5184][1024], k=4, s=2 (fp16 io) ----------
// Batch-PAIRS on lanes (half2 loads -> float2), 4-oc tile, pk-fma inner.
// grid 1152 = (bg8 * 9opy)*16ocg, 1 wave/block.
__global__ __launch_bounds__(64, 3) void conv2_k(const __half2* __restrict__ in2,
                                                 const float* __restrict__ wt,   // wt2n
                                                 const float* __restrict__ bias,
                                                 __half2* __restrict__ out2) {
  const int bid = blockIdx.x;
  const int ocg = bid & 15;
  const int r   = bid >> 4;
  const int opy = r % 9;
  const int bg  = r / 9;
  const int lane = threadIdx.x;
  const int boff = bg * 64 + lane;          // half2 index: b = bg*128 + 2*lane

  f2 acc2[4][9];
#pragma unroll
  for (int o = 0; o < 4; ++o)
#pragma unroll
    for (int ox = 0; ox < 9; ++ox) acc2[o][ox] = (f2){0.f, 0.f};

#pragma unroll 1
  for (int ic = 0; ic < 32; ++ic) {
#pragma unroll
    for (int ky = 0; ky < 4; ++ky) {
      const float* wp = wt + ((ic * 4 + ky) * 16 + ocg) * 16;
      f2 wk2[16];
#pragma unroll
      for (int q = 0; q < 16; ++q) { float wv = wp[q]; wk2[q] = (f2){wv, wv}; }
      const int rowfeat = ic * 400 + (2 * opy + ky) * 20;
      f2 iv2[20];
#pragma unroll
      for (int c = 0; c < 20; ++c) {
        __half2 h = in2[(rowfeat + c) * 512 + boff];
        iv2[c].x = __half2float(h.x);
        iv2[c].y = __half2float(h.y);
      }
#pragma unroll
      for (int o = 0; o < 4; ++o)
#pragma unroll
        for (int ox = 0; ox < 9; ++ox)
#pragma unroll
          for (int kx = 0; kx < 4; ++kx)
            pkfma(acc2[o][ox], iv2[2 * ox + kx], wk2[o * 4 + kx]);
    }
  }

#pragma unroll
  for (int o = 0; o < 4; ++o) {
    const int oc = ocg * 4 + o;
    const float bj = bias[oc];
#pragma unroll
    for (int ox = 0; ox < 9; ++ox) {
      float v0 = acc2[o][ox].x + bj;
      float v1 = acc2[o][ox].y + bj;
      __half2 hv;
      hv.x = __float2half(v0 > 0.f ? v0 : 0.f);
      hv.y = __float2half(v1 > 0.f ? v1 : 0.f);
      out2[(oc * 81 + opy * 9 + ox) * 512 + boff] = hv;
    }
  }
}

// ---------------- conv3: c2t[5184][1024] -> c3t[3136][1024], k=3, s=1 (fp16 io) ----------
// grid 896 = (bg8 * 7opy)*16ocg.
__global__ __launch_bounds__(64, 4) void conv3_k(const __half2* __restrict__ in2,
                                                 const float* __restrict__ wt,   // wt3n
                                                 const float* __restrict__ bias,
                                                 __half2* __restrict__ out2) {
  const int bid = blockIdx.x;
  const int ocg = bid & 15;
  const int r   = bid >> 4;
  const int opy = r % 7;
  const int bg  = r / 7;
  const int lane = threadIdx.x;
  const int boff = bg * 64 + lane;

  f2 acc2[4][7];
#pragma unroll
  for (int o = 0; o < 4; ++o)
#pragma unroll
    for (int ox = 0; ox < 7; ++ox) acc2[o][ox] = (f2){0.f, 0.f};

#pragma unroll 1
  for (int ic = 0; ic < 64; ++ic) {
#pragma unroll
    for (int ky = 0; ky < 3; ++ky) {
      const float* wp = wt + ((ic * 3 + ky) * 16 + ocg) * 12;
      f2 wk2[12];
#pragma unroll
      for (int q = 0; q < 12; ++q) { float wv = wp[q]; wk2[q] = (f2){wv, wv}; }
      const int rowfeat = ic * 81 + (opy + ky) * 9;
      f2 iv2[9];
#pragma unroll
      for (int c = 0; c < 9; ++c) {
        __half2 h = in2[(rowfeat + c) * 512 + boff];
        iv2[c].x = __half2float(h.x);
        iv2[c].y = __half2float(h.y);
      }
#pragma unroll
      for (int o = 0; o < 4; ++o)
#pragma unroll
        for (int ox = 0; ox < 7; ++ox)
#pragma unroll
          for (int kx = 0; kx < 3; ++kx)
            pkfma(acc2[o][ox], iv2[ox + kx], wk2[o * 3 + kx]);
    }
  }

#pragma unroll
  for (int o = 0; o < 4; ++o) {
    const int oc = ocg * 4 + o;
    const float bj = bias[oc];
#pragma unroll
    for (int ox = 0; ox < 7; ++ox) {
      float v0 = acc2[o][ox].x + bj;
      float v1 = acc2[o][ox].y + bj;
      __half2 hv;
      hv.x = __float2half(v0 > 0.f ? v0 : 0.f);
      hv.y = __float2half(v1 > 0.f ? v1 : 0.f);
      out2[(oc * 49 + opy * 7 + ox) * 512 + boff] = hv;
    }
  }
}

// ---------------- fc1a: c3t[3136][1024] @ fw1[3136][256] -> part[8][256][1024] ------------
// Batch-pairs on lanes; j-tile 8; grid 2048 = (bg8*32jg)*8kc. Plain float2 fma
// (weight dup per k would cancel pk gains here).
__global__ __launch_bounds__(64) void fc1a_k(const __half2* __restrict__ a2,
                                             const float* __restrict__ w,
                                             float* __restrict__ part) {
  const int bid = blockIdx.x;
  const int kc = bid & 7;
  const int r  = bid >> 3;
  const int jg = r & 31;
  const int bg = r >> 5;
  const int lane = threadIdx.x;
  const int boff = bg * 64 + lane;

  f2 acc2[8];
#pragma unroll
  for (int j = 0; j < 8; ++j) acc2[j] = (f2){0.f, 0.f};

  const __half2* ap = a2 + kc * 392 * 512 + boff;
  const float* wp0 = w + kc * 392 * 256 + jg * 8;

#pragma unroll 2
  for (int k = 0; k < 392; ++k) {
    __half2 h = ap[k * 512];
    float ax = __half2float(h.x), ay = __half2float(h.y);
    const float* wp = wp0 + k * 256;
#pragma unroll
    for (int j = 0; j < 8; ++j) {
      float wv = wp[j];
      acc2[j].x = fmaf(ax, wv, acc2[j].x);
      acc2[j].y = fmaf(ay, wv, acc2[j].y);
    }
  }
#pragma unroll
  for (int j = 0; j < 8; ++j) {
    float2 v = {acc2[j].x, acc2[j].y};
    *(float2*)&part[(kc * 256 + jg * 8 + j) * 1024 + bg * 128 + lane * 2] = v;
  }
}

// ---------------- fc1b: reduce 8 partials + bias + relu -> h_t[256][1024] ----------------
__global__ __launch_bounds__(256) void fc1b_k(const float* __restrict__ part,
                                              const float* __restrict__ bias,
                                              float* __restrict__ h) {
  int idx = blockIdx.x * 256 + threadIdx.x;   // j*1024 + b
  float s = bias[idx >> 10];
#pragma unroll
  for (int c = 0; c < 8; ++c) s += part[c * 262144 + idx];
  h[idx] = s > 0.f ? s : 0.f;
}

// ---------------- fc2 + softmax + dist/res (reads h_t[k][b]) ----------------
__global__ __launch_bounds__(256) void fc2_k(const float* __restrict__ h,     // [256][1024]
                                             const float* __restrict__ w,     // [256][51]
                                             const float* __restrict__ bias,
                                             const float* __restrict__ z,
                                             float* __restrict__ dist,        // [1024][6][51]
                                             float* __restrict__ res) {       // [1024][6]
  const int tid = threadIdx.x;
  const int j   = tid & 63;
  const int b   = blockIdx.x * 4 + RL(tid >> 6);
  const int jc = j < 51 ? j : 50;
  float acc = bias[jc];
#pragma unroll 4
  for (int k = 0; k < 256; ++k)
    acc = fmaf(h[k * 1024 + b], w[k * 51 + jc], acc);
  float logit = (j < 51) ? acc : -1e30f;
  float m = logit;
#pragma unroll
  for (int o = 32; o > 0; o >>= 1) m = fmaxf(m, __shfl_xor(m, o, 64));
  float e = (j < 51) ? __expf(logit - m) : 0.f;
  float ssum = e;
#pragma unroll
  for (int o = 32; o > 0; o >>= 1) ssum += __shfl_xor(ssum, o, 64);
  float p = e / ssum;
  float zv = (j < 51) ? z[jc] : 0.f;
  float rz = p * zv;
#pragma unroll
  for (int o = 32; o > 0; o >>= 1) rz += __shfl_xor(rz, o, 64);
  if (j < 51) {
    float* db = dist + b * 6 * 51 + j;
#pragma unroll
    for (int n = 0; n < 6; ++n) db[n * 51] = p;
  }
  if (j < 6) res[b * 6 + j] = rz;
}

extern "C" void kernel_launch(void* const* d_in, const int* in_sizes, int n_in,
                              void* d_out, int out_size, void* d_ws, size_t ws_size,
                              hipStream_t stream) {
  const float* x   = (const float*)d_in[0];
  const float* cw1 = (const float*)d_in[1];
  const float* cb1 = (const float*)d_in[2];
  const float* cw2 = (const float*)d_in[3];
  const float* cb2 = (const float*)d_in[4];
  const float* cw3 = (const float*)d_in[5];
  const float* cb3 = (const float*)d_in[6];
  const float* fw1 = (const float*)d_in[7];
  const float* fb1 = (const float*)d_in[8];
  const float* fw2 = (const float*)d_in[9];
  const float* fb2 = (const float*)d_in[10];
  const float* z   = (const float*)d_in[11];

  float* ws = (float*)d_ws;
  // c1h : [0, 6553600)          1024*12800 halfs
  // c1t : [6553600, 13107200)   12800*1024 halfs
  // c2t : [13107200, 15761408)  5184*1024 halfs
  // c3t : [15761408, 17367040)  3136*1024 halfs
  // part: [0, 2097152)          8*256*1024 fp32 (reuses dead c1h)
  // h_t : [2097152, 2359296)    256*1024 fp32
  __half* c1h = (__half*)ws;
  __half* c1t = (__half*)(ws + 6553600);
  __half* c2t = (__half*)(ws + 13107200);
  __half* c3t = (__half*)(ws + 15761408);
  float*  pw  = ws;
  float*  h_t = ws + 2097152;

  float* wt2n = (float*)d_out;            // 32768 floats (d_out scratch)
  float* wt3n = (float*)d_out + 32768;    // 36864 floats

  float* dist = (float*)d_out;
  float* res  = dist + 1024 * 6 * 51;

  wprep_k<<<144, 256, 0, stream>>>(cw2, cw3, wt2n, wt3n);
  conv1_k<<<1024, 256, 0, stream>>>(x, cw1, cb1, c1h);
  t1_k<<<dim3(200, 16), 256, 0, stream>>>(c1h, c1t);
  conv2_k<<<1152, 64, 0, stream>>>((const __half2*)c1t, wt2n, cb2, (__half2*)c2t);
  conv3_k<<<896, 64, 0, stream>>>((const __half2*)c2t, wt3n, cb3, (__half2*)c3t);
  fc1a_k<<<2048, 64, 0, stream>>>((const __half2*)c3t, fw1, pw);
  fc1b_k<<<1024, 256, 0, stream>>>(pw, fb1, h_t);
  fc2_k<<<256, 256, 0, stream>>>(h_t, fw2, fb2, z, dist, res);
}